// Round 4
// baseline (64699.744 us; speedup 1.0000x reference)
//
#include <hip/hip_runtime.h>
#include <hip/hip_bf16.h>
#include <math.h>

using bf16 = __hip_bfloat16;
using short8 = __attribute__((ext_vector_type(8))) short;
using f32x4  = __attribute__((ext_vector_type(4))) float;

#define B_     128
#define T_     64
#define EMB_   1536
#define ACT_   12
#define STOCH_ 32
#define DETER_ 1024
#define HID_   1024
#define GRUN_  3072
#define GRUK_  2048
#define OBSK_  2560
#define OUTW_  1216   // 6*STOCH + DETER

// canonical f32 param block offsets (floats) -- W1 kept f32 for LN path, plus bf16 copies
#define Pb1   45056
#define Pg1   46080
#define Pbn1  47104
#define Pbg   48128
#define Pgg   51200
#define Pbng  54272
#define Pb3   57344
#define Pg3   62464
#define Pbn3  67584
#define Pb4   72704
#define Pb5   73024
#define Pg5   74048
#define Pbn5  75072
#define Pb6   76096
#define PTOT  76160

__device__ inline float bf2f(bf16 v){ return __bfloat162float(v); }
__device__ inline bf16  f2bf(float v){ return __float2bfloat16(v); }
__device__ inline float elu_(float x){ return x > 0.f ? x : expm1f(x); }
__device__ inline float sigm_(float x){ return 1.f/(1.f+expf(-x)); }
__device__ inline float softplus_(float x){ return fmaxf(x,0.f) + log1pf(expf(-fabsf(x))); }
__device__ inline void stout(void* out, int dt, size_t i, float v){
  if(dt) ((bf16*)out)[i] = f2bf(v); else ((float*)out)[i] = v;
}
__device__ inline float maskv(const void* isf, int enc, int idx){
  float fv;
  if(enc==0)      fv = (float)((const int*)isf)[idx];
  else if(enc==1) fv = (float)((const unsigned char*)isf)[idx];
  else if(enc==2) fv = bf2f(((const bf16*)isf)[idx]);
  else            fv = ((const float*)isf)[idx];
  return (fv != 0.f) ? 0.f : 1.f;
}

__device__ inline void block_reduce2(float& a, float& b, float* sm){
  __syncthreads();
  for(int off=32; off>0; off>>=1){
    a += __shfl_down(a, off);
    b += __shfl_down(b, off);
  }
  int w = threadIdx.x >> 6;
  if((threadIdx.x & 63) == 0){ sm[2*w] = a; sm[2*w+1] = b; }
  __syncthreads();
  a = sm[0]+sm[2]+sm[4]+sm[6];
  b = sm[1]+sm[3]+sm[5]+sm[7];
}

// ---- device-scope grid barrier (all 256 blocks co-resident: 1/CU) ----
__device__ inline void gbar(int* cnt, int* ep){
  __syncthreads();
  if(threadIdx.x == 0){
    __threadfence();                               // flush this XCD's dirty L2 lines
    int target = (++(*ep)) * 256;
    __hip_atomic_fetch_add(cnt, 1, __ATOMIC_ACQ_REL, __HIP_MEMORY_SCOPE_AGENT);
    while(__hip_atomic_load(cnt, __ATOMIC_ACQUIRE, __HIP_MEMORY_SCOPE_AGENT) < target)
      __builtin_amdgcn_s_sleep(1);
    __threadfence();                               // invalidate local caches
  }
  __syncthreads();
}

// ---- detect float dtype from embed buffer: dflag[0] = 1 if bf16, 0 if f32 ----
__global__ void k_detect_dtype(const unsigned short* emb, int* dflag){
  __shared__ int cnt;
  if(threadIdx.x==0) cnt = 0;
  __syncthreads();
  int c = 0;
  for(int i=threadIdx.x; i<2048; i+=256){
    unsigned short u = emb[2*i];
    int exp8 = (u >> 7) & 0xFF;
    if(exp8 > 140) c++;
  }
  atomicAdd(&cnt, c);
  __syncthreads();
  if(threadIdx.x==0) dflag[0] = (cnt < 100) ? 1 : 0;
}

// ---- detect is_first encoding: dflag[1] = 0 int32, 1 uint8, 2 bf16, 3 f32 ----
__global__ void k_detect_isf(const unsigned char* isf, int* dflag){
  __shared__ int f_bf, f_f32, f_u8;
  if(threadIdx.x==0){ f_bf=0; f_f32=0; f_u8=0; }
  __syncthreads();
  for(int i=threadIdx.x; i<B_*T_; i+=256){
    unsigned char c = isf[i];
    if(c == 0x3F){
      if((i & 3) == 1) atomicOr(&f_bf, 1);
      else if((i & 3) == 3) atomicOr(&f_f32, 1);
    }
    if(c == 1 && (i & 3) != 0) atomicOr(&f_u8, 1);
  }
  __syncthreads();
  if(threadIdx.x==0)
    dflag[1] = f_bf ? 2 : (f_f32 ? 3 : (f_u8 ? 1 : 0));
}

__global__ void k_zero_i(int* p){
  if(threadIdx.x < 16) p[threadIdx.x] = 0;
}

// ---- batched param conversion -> canonical f32 block ----
struct PDesc { const void* src[15]; int cum[16]; };
__global__ __launch_bounds__(256) void k_params(PDesc pd, float* dst, const int* dflag){
  int g = blockIdx.x*256 + threadIdx.x;
  if(g >= PTOT) return;
  int dt = dflag[0];
  int s = 0;
  while(g >= pd.cum[s+1]) s++;
  int off = g - pd.cum[s];
  dst[g] = dt ? bf2f(((const bf16*)pd.src[s])[off]) : ((const float*)pd.src[s])[off];
}

__global__ void k_cvt_bf(const void* src, bf16* dst, int n, const int* dflag){
  int dt = dflag[0];
  int i0 = (blockIdx.x*256 + threadIdx.x)*4;
  #pragma unroll
  for(int k=0;k<4;k++){
    int i = i0+k;
    if(i < n) dst[i] = dt ? ((const bf16*)src)[i] : f2bf(((const float*)src)[i]);
  }
}

// ---- tiled transpose: src[K][N] -> dst[N][K] (bf16 canonical), head = blockIdx.y ----
__global__ __launch_bounds__(256) void k_transpose(const void* src, bf16* dst, int K, int N, const int* dflag){
  __shared__ unsigned short t[64][72];
  int dt = dflag[0];
  int tilesN = N/64;
  int tk = blockIdx.x / tilesN, tn = blockIdx.x % tilesN;
  size_t hoff = (size_t)blockIdx.y * K * N;
  unsigned short* d = (unsigned short*)dst + hoff;
  int tx = threadIdx.x & 63, ty0 = threadIdx.x >> 6;
  int k0 = tk*64, n0 = tn*64;
  #pragma unroll
  for(int i=0;i<16;i++){
    int ty = ty0*16+i;
    size_t off = hoff + (size_t)(k0+ty)*N + n0+tx;
    unsigned short v;
    if(dt) v = ((const unsigned short*)src)[off];
    else { bf16 b = f2bf(((const float*)src)[off]); v = *(unsigned short*)&b; }
    t[ty][tx] = v;
  }
  __syncthreads();
  #pragma unroll
  for(int i=0;i<16;i++){ int ty = ty0*16+i; d[(size_t)(n0+ty)*K + k0+tx] = t[tx][ty]; }
}

// ---- MFMA tile GEMM: 128 x (16*CF) output, K split over 4 waves, LDS reduce ----
template<int CF>
__device__ inline void gemm_tile(const bf16* A0, int s0,
                                 const bf16* BT, int ldb,
                                 float* Cdst, int ldc,
                                 int k0, int kc, float* red)
{
  int tid = threadIdx.x;
  int wave = tid >> 6, lane = tid & 63;
  int quad = lane >> 4, lo = lane & 15;
  int kw0 = k0 + wave*(kc>>2), kw1 = kw0 + (kc>>2);
  f32x4 acc[8][CF];
  #pragma unroll
  for(int rf=0;rf<8;rf++)
    #pragma unroll
    for(int c=0;c<CF;c++) acc[rf][c] = (f32x4)0.f;
  for(int kk=kw0; kk<kw1; kk+=32){
    int kf = kk + quad*8;
    short8 af[8], bfg[CF];
    #pragma unroll
    for(int rf=0;rf<8;rf++)
      af[rf] = *(const short8*)(const void*)(A0 + (size_t)(16*rf+lo)*s0 + kf);
    #pragma unroll
    for(int c=0;c<CF;c++)
      bfg[c] = *(const short8*)(const void*)(BT + (size_t)(16*c+lo)*ldb + kf);
    #pragma unroll
    for(int rf=0;rf<8;rf++)
      #pragma unroll
      for(int c=0;c<CF;c++)
        acc[rf][c] = __builtin_amdgcn_mfma_f32_16x16x32_bf16(af[rf], bfg[c], acc[rf][c], 0,0,0);
  }
  const int SLOT = 8*CF;
  if(wave >= 2){
    #pragma unroll
    for(int rf=0;rf<8;rf++)
      #pragma unroll
      for(int c=0;c<CF;c++)
        *(f32x4*)&red[(((wave-2)*SLOT) + rf*CF + c)*256 + lane*4] = acc[rf][c];
  }
  __syncthreads();
  if(wave < 2){
    #pragma unroll
    for(int rf=0;rf<8;rf++)
      #pragma unroll
      for(int c=0;c<CF;c++)
        acc[rf][c] += *(const f32x4*)&red[((wave*SLOT) + rf*CF + c)*256 + lane*4];
  }
  __syncthreads();
  if(wave < 2){
    #pragma unroll
    for(int rf=0;rf<8;rf++)
      #pragma unroll
      for(int c=0;c<CF;c++)
        *(f32x4*)&red[((wave*SLOT) + rf*CF + c)*256 + lane*4] = acc[rf][c];
  }
  __syncthreads();
  const int tpr = 4*CF;          // threads per row (4 cols each)
  const int rpp = 256/tpr;       // rows per pass
  #pragma unroll
  for(int i=0;i<128/rpp;i++){
    int r = tid/tpr + rpp*i;
    int col0 = (tid%tpr)*4;
    int rf = r>>4, rr = r&15, q = rr>>2, g = rr&3;
    f32x4 v;
    #pragma unroll
    for(int j=0;j<4;j++){
      int col = col0+j; int c = col>>4, lo2 = col&15;
      int lane2 = q*16+lo2;
      v[j] = red[(rf*CF + c)*256 + lane2*4 + g]
           + red[(SLOT + rf*CF + c)*256 + lane2*4 + g];
    }
    *(f32x4*)(Cdst + (size_t)r*ldc + col0) = v;
  }
}

// ---- step_in: input MLP (K=44) + LN + elu -> A2[0:1024]; masked deter -> determ, A2[1024:2048] ----
__device__ inline void stepin_dev(int b, int t, const float* stochLDS, bool zero,
    const void* action, const void* isf, int enc, int dt,
    const float* paramF, const bf16* W1B,
    const float* deter, float* determ, bf16* A2, float* lds)
{
  float* in44 = lds;         // 48
  float* sm   = lds + 64;    // 8
  int tid = threadIdx.x;
  float m = maskv(isf, enc, b*T_ + t);
  if(tid < 32) in44[tid] = zero ? 0.f : stochLDS[tid]*m;
  else if(tid < 44){
    int i = (b*T_+t)*ACT_ + (tid-32);
    float av = dt ? bf2f(((const bf16*)action)[i]) : ((const float*)action)[i];
    in44[tid] = av*m;
  }
  __syncthreads();
  float z[4]; float s=0.f, s2=0.f;
  #pragma unroll
  for(int i=0;i<4;i++){
    int h = tid + 256*i;
    float acc = paramF[Pb1 + h];
    for(int k=0;k<44;k++) acc += in44[k]*bf2f(W1B[k*HID_ + h]);
    z[i]=acc; s+=acc; s2+=acc*acc;
  }
  block_reduce2(s, s2, sm);
  float mean = s/HID_, var = s2/HID_ - mean*mean;
  float rstd = rsqrtf(fmaxf(var,0.f) + 1e-5f);
  #pragma unroll
  for(int i=0;i<4;i++){
    int h = tid + 256*i;
    float xv = (z[i]-mean)*rstd*paramF[Pg1+h] + paramF[Pbn1+h];
    A2[(size_t)b*GRUK_ + h] = f2bf(elu_(xv));
    float dm = zero ? 0.f : deter[b*DETER_+h]*m;
    determ[b*DETER_+h] = dm;
    A2[(size_t)b*GRUK_ + HID_ + h] = f2bf(dm);
  }
}

// ---- GRU: reduce z2 parts + bias, LN over 3072, gates -> deter/deterB/out ----
__device__ inline void gru_dev(int b, int t, const float* z2p, const float* paramF, int dt,
    const float* determ, float* deter, bf16* deterB, void* out, float* lds)
{
  float* sm = lds;
  int tid = threadIdx.x;
  float zz[12]; float s=0.f, s2=0.f;
  #pragma unroll
  for(int i=0;i<12;i++){
    int h = tid + 256*i;
    float acc = paramF[Pbg + h]
              + z2p[(size_t)b*GRUN_ + h]
              + z2p[(size_t)(B_ + b)*GRUN_ + h];
    zz[i]=acc; s+=acc; s2+=acc*acc;
  }
  block_reduce2(s, s2, sm);
  float mean = s/GRUN_, var = s2/GRUN_ - mean*mean;
  float rstd = rsqrtf(fmaxf(var,0.f) + 1e-5f);
  #pragma unroll
  for(int j=0;j<4;j++){
    int h0 = tid + 256*j;
    float lnr = (zz[j]   - mean)*rstd*paramF[Pgg+h0     ] + paramF[Pbng+h0     ];
    float lnc = (zz[j+4] - mean)*rstd*paramF[Pgg+h0+1024] + paramF[Pbng+h0+1024];
    float lnu = (zz[j+8] - mean)*rstd*paramF[Pgg+h0+2048] + paramF[Pbng+h0+2048];
    float reset = sigm_(lnr);
    float cand  = tanhf(reset*lnc);
    float upd   = sigm_(lnu - 1.f);          // UPDATE_BIAS
    float dn = upd*cand + (1.f-upd)*determ[b*DETER_+h0];
    deter[b*DETER_+h0]  = dn;
    deterB[b*DETER_+h0] = f2bf(dn);
    stout(out, dt, ((size_t)b*T_+t)*OUTW_ + 192 + h0, dn);
  }
}

// ---- tail: z3/z5 reduce + LN + elu, dist matmuls, outputs, fused step_in(t+1) ----
__device__ inline void tail_dev(int b, int t, int idx,
    const float* z3p, const float* z5dp, const float* z5e,
    const float* paramF, const bf16* W4B, const bf16* W6B, const bf16* W1B,
    int dt, int enc, const void* action, const void* isf,
    const float* deter, float* determ, bf16* A2, void* out, float* lds)
{
  float* hs  = lds;            // 1024
  float* xo  = lds + 1024;     // 1024
  float* red = lds + 2048;     // 256
  float* dsO = lds + 2304;     // 128
  float* sm  = lds + 2432;     // 8
  int tid = threadIdx.x;
  float z3v[4], z5v[4]; float s3=0.f,q3=0.f,s5=0.f,q5=0.f;
  #pragma unroll
  for(int i=0;i<4;i++){
    int h = tid + 256*i;
    float a3 = z3p[(size_t)b*HID_ + h] + z3p[(size_t)(B_+b)*HID_ + h] + paramF[Pb3 + idx*HID_ + h];
    z3v[i]=a3; s3+=a3; q3+=a3*a3;
    float a5 = z5dp[(size_t)b*HID_ + h] + z5dp[(size_t)(B_+b)*HID_ + h]
             + z5e[(size_t)b*HID_ + h] + paramF[Pb5 + h];
    z5v[i]=a5; s5+=a5; q5+=a5*a5;
  }
  block_reduce2(s3, q3, sm);
  block_reduce2(s5, q5, sm);
  float m3=s3/HID_, v3=q3/HID_-m3*m3, r3=rsqrtf(fmaxf(v3,0.f)+1e-5f);
  float m5=s5/HID_, v5=q5/HID_-m5*m5, r5=rsqrtf(fmaxf(v5,0.f)+1e-5f);
  #pragma unroll
  for(int i=0;i<4;i++){
    int h = tid + 256*i;
    hs[h] = elu_((z3v[i]-m3)*r3*paramF[Pg3+idx*HID_+h] + paramF[Pbn3+idx*HID_+h]);
    xo[h] = elu_((z5v[i]-m5)*r5*paramF[Pg5+h] + paramF[Pbn5+h]);
  }
  __syncthreads();
  int j = tid & 63, cch = tid >> 6;
  {
    const bf16* W = W4B + (size_t)idx*HID_*64;
    float a = 0.f;
    for(int k=cch*256; k<cch*256+256; k++) a += hs[k]*bf2f(W[k*64 + j]);
    red[tid] = a;
    __syncthreads();
    if(tid < 64) dsO[tid] = red[tid]+red[tid+64]+red[tid+128]+red[tid+192] + paramF[Pb4+idx*64+tid];
    __syncthreads();
    a = 0.f;
    for(int k=cch*256; k<cch*256+256; k++) a += xo[k]*bf2f(W6B[k*64 + j]);
    red[tid] = a;
    __syncthreads();
    if(tid < 64) dsO[64+tid] = red[tid]+red[tid+64]+red[tid+128]+red[tid+192] + paramF[Pb6+tid];
    __syncthreads();
  }
  size_t ob = ((size_t)b*T_ + t)*OUTW_;
  if(tid < 32){
    float pm = dsO[tid];
    float ps = softplus_(dsO[32+tid]) + 0.1f;
    float om = dsO[64+tid];
    float os = softplus_(dsO[96+tid]) + 0.1f;
    stout(out, dt, ob+tid,      om);   // omean
    stout(out, dt, ob+32+tid,   os);   // ostd
    stout(out, dt, ob+64+tid,   om);   // post_stoch
    stout(out, dt, ob+96+tid,   pm);   // pmean
    stout(out, dt, ob+128+tid,  ps);   // pstd
    stout(out, dt, ob+160+tid,  pm);   // prior_stoch
  }
  if(t+1 < T_)
    stepin_dev(b, t+1, dsO+64, false, action, isf, enc, dt, paramF, W1B,
               deter, determ, A2, lds + 2560);
}

// ---- persistent scan kernel: grid 256 x 256, 4 grid barriers per step ----
__global__ __launch_bounds__(256) void k_persist(
    const void* action, const void* isf, const int* dflag, const float* paramF,
    const bf16* W1B, const bf16* W4B, const bf16* W6B,
    const bf16* embB, const bf16* WgT, const bf16* W3T, const bf16* W5T,
    bf16* A2, bf16* deterB, float* deter, float* determ,
    float* z2p, float* z3p, float* z5dp, float* z5e,
    void* out, const int* ens_index, int* cnt)
{
  __shared__ float lds[8192];   // 32 KB: gemm reduce / tail scratch
  int bid = blockIdx.x;
  int dt = dflag[0], enc = dflag[1];
  int ep = 0;

  // init: step_in(t=0) with zero carry
  if(bid < B_)
    stepin_dev(bid, 0, nullptr, true, action, isf, enc, dt, paramF, W1B,
               nullptr, determ, A2, lds);
  gbar(cnt, &ep);

  for(int t=0; t<T_; t++){
    int idx = ens_index[t];
    // ---- G1: GRU GEMM (192 blocks) + z5 embed part (64 blocks) ----
    if(bid < 192){
      int ct = bid % 96, part = bid / 96;
      gemm_tile<2>(A2, GRUK_,
                   WgT + (size_t)ct*32*GRUK_, GRUK_,
                   z2p + (size_t)part*B_*GRUN_ + ct*32, GRUN_,
                   part*1024, 1024, lds);
    } else {
      int ct = bid - 192;      // 64 tiles w16
      gemm_tile<1>(embB + (size_t)t*EMB_, T_*EMB_,
                   W5T + (size_t)ct*16*OBSK_ + 1024, OBSK_,
                   z5e + ct*16, HID_,
                   0, 1536, lds);
    }
    gbar(cnt, &ep);
    // ---- GRU ----
    if(bid < B_)
      gru_dev(bid, t, z2p, paramF, dt, determ, deter, deterB, out, lds);
    gbar(cnt, &ep);
    // ---- G2: z3 (128 blocks) + z5 deter part (128 blocks), w16, Ksplit2 ----
    if(bid < 128){
      int ct = bid & 63, part = bid >> 6;
      gemm_tile<1>(deterB, DETER_,
                   W3T + (size_t)idx*DETER_*HID_ + (size_t)ct*16*DETER_, DETER_,
                   z3p + (size_t)part*B_*HID_ + ct*16, HID_,
                   part*512, 512, lds);
    } else {
      int b2 = bid - 128; int ct = b2 & 63, part = b2 >> 6;
      gemm_tile<1>(deterB, DETER_,
                   W5T + (size_t)ct*16*OBSK_, OBSK_,
                   z5dp + (size_t)part*B_*HID_ + ct*16, HID_,
                   part*512, 512, lds);
    }
    gbar(cnt, &ep);
    // ---- TAIL: heads + outputs + step_in(t+1) ----
    if(bid < B_)
      tail_dev(bid, t, idx, z3p, z5dp, z5e, paramF, W4B, W6B, W1B,
               dt, enc, action, isf, deter, determ, A2, out, lds);
    gbar(cnt, &ep);
  }
}

extern "C" void kernel_launch(void* const* d_in, const int* in_sizes, int n_in,
                              void* d_out, int out_size, void* d_ws, size_t ws_size,
                              hipStream_t stream)
{
  const void* embed  = d_in[0];
  const void* action = d_in[1];
  const void* isf    = d_in[2];
  const int*  ens_ix = (const int*)d_in[3];

  char* ws = (char*)d_ws;
  float* deter  = (float*)(ws + 0);            // 512 KB
  float* determ = (float*)(ws + 524288);       // 512 KB
  bf16*  A2     = (bf16*) (ws + 1048576);      // 512 KB
  bf16*  deterB = (bf16*) (ws + 1572864);      // 256 KB
  float* z2p    = (float*)(ws + 1835008);      // 3 MB (2 parts)
  float* z3p    = (float*)(ws + 4980736);      // 1 MB (2 parts)
  float* z5dp   = (float*)(ws + 6029312);      // 1 MB (2 parts)
  float* z5e    = (float*)(ws + 7077888);      // 512 KB
  bf16*  WgT    = (bf16*) (ws + 7602176);      // 12.6 MB
  bf16*  W3T    = (bf16*) (ws + 20185088);     // 10.5 MB
  bf16*  W5T    = (bf16*) (ws + 30670848);     // 5.2 MB
  float* paramF = (float*)(ws + 35913728);     // 0.30 MB
  bf16*  embB   = (bf16*) (ws + 36218368);     // 25.2 MB
  bf16*  W1B    = (bf16*) (ws + 61384192);     // 88 KB
  bf16*  W4B    = (bf16*) (ws + 61474304);     // 640 KB
  bf16*  W6B    = (bf16*) (ws + 62129664);     // 128 KB
  int*   dflag  = (int*)  (ws + 62260736);
  int*   cnt    = (int*)  (ws + 62260800);

  k_detect_dtype<<<1,256,0,stream>>>((const unsigned short*)embed, dflag);
  k_detect_isf<<<1,256,0,stream>>>((const unsigned char*)isf, dflag);
  k_zero_i<<<1,64,0,stream>>>(cnt);

  PDesc pd;
  const int srcidx[15] = {4,5,6,7, 9,10,11, 13,14,15, 17, 19,20,21, 23};
  const int sizes[15]  = {45056,1024,1024,1024, 3072,3072,3072, 5120,5120,5120,
                          320, 1024,1024,1024, 64};
  int cum = 0;
  for(int i=0;i<15;i++){ pd.src[i] = d_in[srcidx[i]]; pd.cum[i] = cum; cum += sizes[i]; }
  pd.cum[15] = cum;  // 76160
  k_params<<<(PTOT+255)/256, 256, 0, stream>>>(pd, paramF, dflag);

  k_cvt_bf<<<(B_*T_*EMB_)/1024, 256, 0, stream>>>(embed, embB, B_*T_*EMB_, dflag);
  k_cvt_bf<<<44, 256, 0, stream>>>(d_in[4],  W1B, 44*HID_, dflag);
  k_cvt_bf<<<320,256, 0, stream>>>(d_in[16], W4B, 5*HID_*64, dflag);
  k_cvt_bf<<<64, 256, 0, stream>>>(d_in[22], W6B, HID_*64, dflag);

  k_transpose<<<dim3((GRUK_/64)*(GRUN_/64),1), 256, 0, stream>>>(d_in[8],  WgT, GRUK_, GRUN_, dflag);
  k_transpose<<<dim3((DETER_/64)*(HID_/64),5), 256, 0, stream>>>(d_in[12], W3T, DETER_, HID_, dflag);
  k_transpose<<<dim3((OBSK_/64)*(HID_/64),1), 256, 0, stream>>>(d_in[18], W5T, OBSK_, HID_, dflag);

  k_persist<<<256,256,0,stream>>>(action, isf, dflag, paramF, W1B, W4B, W6B,
                                  embB, WgT, W3T, W5T,
                                  A2, deterB, deter, determ,
                                  z2p, z3p, z5dp, z5e,
                                  d_out, ens_ix, cnt);
}

// Round 5
// 20917.163 us; speedup vs baseline: 3.0931x; 3.0931x over previous
//
#include <hip/hip_runtime.h>
#include <hip/hip_bf16.h>
#include <math.h>

using bf16 = __hip_bfloat16;
using short8 = __attribute__((ext_vector_type(8))) short;
using f32x4  = __attribute__((ext_vector_type(4))) float;

#define B_     128
#define T_     64
#define EMB_   1536
#define ACT_   12
#define STOCH_ 32
#define DETER_ 1024
#define HID_   1024
#define GRUN_  3072
#define GRUK_  2048
#define OBSK_  2560
#define OUTW_  1216   // 6*STOCH + DETER

// canonical f32 param block offsets (floats)
#define Pb1   45056
#define Pg1   46080
#define Pbn1  47104
#define Pbg   48128
#define Pgg   51200
#define Pbng  54272
#define Pb3   57344
#define Pg3   62464
#define Pbn3  67584
#define Pb4   72704
#define Pb5   73024
#define Pg5   74048
#define Pbn5  75072
#define Pb6   76096
#define PTOT  76160

__device__ inline float bf2f(bf16 v){ return __bfloat162float(v); }
__device__ inline bf16  f2bf(float v){ return __float2bfloat16(v); }
__device__ inline float elu_(float x){ return x > 0.f ? x : expm1f(x); }
__device__ inline float sigm_(float x){ return 1.f/(1.f+expf(-x)); }
__device__ inline float softplus_(float x){ return fmaxf(x,0.f) + log1pf(expf(-fabsf(x))); }
__device__ inline void stout(void* out, int dt, size_t i, float v){
  if(dt) ((bf16*)out)[i] = f2bf(v); else ((float*)out)[i] = v;
}
__device__ inline float maskv(const void* isf, int enc, int idx){
  float fv;
  if(enc==0)      fv = (float)((const int*)isf)[idx];
  else if(enc==1) fv = (float)((const unsigned char*)isf)[idx];
  else if(enc==2) fv = bf2f(((const bf16*)isf)[idx]);
  else            fv = ((const float*)isf)[idx];
  return (fv != 0.f) ? 0.f : 1.f;
}

// group-local (4-wave, tid=0..255) reduction of two values; sm is group-local
__device__ inline void block_reduce2(float& a, float& b, float* sm, int tid){
  __syncthreads();
  for(int off=32; off>0; off>>=1){
    a += __shfl_down(a, off);
    b += __shfl_down(b, off);
  }
  int w = tid >> 6;
  if((tid & 63) == 0){ sm[2*w] = a; sm[2*w+1] = b; }
  __syncthreads();
  a = sm[0]+sm[2]+sm[4]+sm[6];
  b = sm[1]+sm[3]+sm[5]+sm[7];
}

// ---- grid barrier: relaxed spin (NO per-iteration invalidate), one wb + one inv ----
__device__ inline void gbar(int* cnt, int& ep){
  __syncthreads();
  if(threadIdx.x == 0){
    __builtin_amdgcn_fence(__ATOMIC_RELEASE, "agent");   // writeback dirty L2
    __hip_atomic_fetch_add(cnt, 1, __ATOMIC_RELAXED, __HIP_MEMORY_SCOPE_AGENT);
    int target = (++ep) * 256;
    while(__hip_atomic_load(cnt, __ATOMIC_RELAXED, __HIP_MEMORY_SCOPE_AGENT) < target)
      __builtin_amdgcn_s_sleep(4);
    __builtin_amdgcn_fence(__ATOMIC_ACQUIRE, "agent");   // single invalidate
  }
  __syncthreads();
}

// ---- detect float dtype from embed buffer: dflag[0] = 1 if bf16, 0 if f32 ----
__global__ void k_detect_dtype(const unsigned short* emb, int* dflag){
  __shared__ int cnt;
  if(threadIdx.x==0) cnt = 0;
  __syncthreads();
  int c = 0;
  for(int i=threadIdx.x; i<2048; i+=256){
    unsigned short u = emb[2*i];
    int exp8 = (u >> 7) & 0xFF;
    if(exp8 > 140) c++;
  }
  atomicAdd(&cnt, c);
  __syncthreads();
  if(threadIdx.x==0) dflag[0] = (cnt < 100) ? 1 : 0;
}

// ---- detect is_first encoding: dflag[1] = 0 int32, 1 uint8, 2 bf16, 3 f32 ----
__global__ void k_detect_isf(const unsigned char* isf, int* dflag){
  __shared__ int f_bf, f_f32, f_u8;
  if(threadIdx.x==0){ f_bf=0; f_f32=0; f_u8=0; }
  __syncthreads();
  for(int i=threadIdx.x; i<B_*T_; i+=256){
    unsigned char c = isf[i];
    if(c == 0x3F){
      if((i & 3) == 1) atomicOr(&f_bf, 1);
      else if((i & 3) == 3) atomicOr(&f_f32, 1);
    }
    if(c == 1 && (i & 3) != 0) atomicOr(&f_u8, 1);
  }
  __syncthreads();
  if(threadIdx.x==0)
    dflag[1] = f_bf ? 2 : (f_f32 ? 3 : (f_u8 ? 1 : 0));
}

__global__ void k_zero_i(int* p){
  if(threadIdx.x < 16) p[threadIdx.x] = 0;
}

// ---- batched param conversion -> canonical f32 block ----
struct PDesc { const void* src[15]; int cum[16]; };
__global__ __launch_bounds__(256) void k_params(PDesc pd, float* dst, const int* dflag){
  int g = blockIdx.x*256 + threadIdx.x;
  if(g >= PTOT) return;
  int dt = dflag[0];
  int s = 0;
  while(g >= pd.cum[s+1]) s++;
  int off = g - pd.cum[s];
  dst[g] = dt ? bf2f(((const bf16*)pd.src[s])[off]) : ((const float*)pd.src[s])[off];
}

__global__ void k_cvt_bf(const void* src, bf16* dst, int n, const int* dflag){
  int dt = dflag[0];
  int i0 = (blockIdx.x*256 + threadIdx.x)*4;
  #pragma unroll
  for(int k=0;k<4;k++){
    int i = i0+k;
    if(i < n) dst[i] = dt ? ((const bf16*)src)[i] : f2bf(((const float*)src)[i]);
  }
}

// ---- tiled transpose: src[K][N] -> dst[N][K] (bf16 canonical), head = blockIdx.y ----
__global__ __launch_bounds__(256) void k_transpose(const void* src, bf16* dst, int K, int N, const int* dflag){
  __shared__ unsigned short t[64][72];
  int dt = dflag[0];
  int tilesN = N/64;
  int tk = blockIdx.x / tilesN, tn = blockIdx.x % tilesN;
  size_t hoff = (size_t)blockIdx.y * K * N;
  unsigned short* d = (unsigned short*)dst + hoff;
  int tx = threadIdx.x & 63, ty0 = threadIdx.x >> 6;
  int k0 = tk*64, n0 = tn*64;
  #pragma unroll
  for(int i=0;i<16;i++){
    int ty = ty0*16+i;
    size_t off = hoff + (size_t)(k0+ty)*N + n0+tx;
    unsigned short v;
    if(dt) v = ((const unsigned short*)src)[off];
    else { bf16 b = f2bf(((const float*)src)[off]); v = *(unsigned short*)&b; }
    t[ty][tx] = v;
  }
  __syncthreads();
  #pragma unroll
  for(int i=0;i<16;i++){ int ty = ty0*16+i; d[(size_t)(n0+ty)*K + k0+tx] = t[tx][ty]; }
}

// ---- MFMA tile GEMM (4-wave group): 128 x (16*CF) tile, K split over 4 waves ----
template<int CF>
__device__ inline void gemm_tile(const bf16* A0, int s0,
                                 const bf16* BT, int ldb,
                                 float* Cdst, int ldc,
                                 int k0, int kc, float* red, int tid)
{
  int wave = tid >> 6, lane = tid & 63;
  int quad = lane >> 4, lo = lane & 15;
  int kw0 = k0 + wave*(kc>>2), kw1 = kw0 + (kc>>2);
  f32x4 acc[8][CF];
  #pragma unroll
  for(int rf=0;rf<8;rf++)
    #pragma unroll
    for(int c=0;c<CF;c++) acc[rf][c] = (f32x4)0.f;
  for(int kk=kw0; kk<kw1; kk+=32){
    int kf = kk + quad*8;
    short8 af[8], bfg[CF];
    #pragma unroll
    for(int rf=0;rf<8;rf++)
      af[rf] = *(const short8*)(const void*)(A0 + (size_t)(16*rf+lo)*s0 + kf);
    #pragma unroll
    for(int c=0;c<CF;c++)
      bfg[c] = *(const short8*)(const void*)(BT + (size_t)(16*c+lo)*ldb + kf);
    #pragma unroll
    for(int rf=0;rf<8;rf++)
      #pragma unroll
      for(int c=0;c<CF;c++)
        acc[rf][c] = __builtin_amdgcn_mfma_f32_16x16x32_bf16(af[rf], bfg[c], acc[rf][c], 0,0,0);
  }
  const int SLOT = 8*CF;
  if(wave >= 2){
    #pragma unroll
    for(int rf=0;rf<8;rf++)
      #pragma unroll
      for(int c=0;c<CF;c++)
        *(f32x4*)&red[(((wave-2)*SLOT) + rf*CF + c)*256 + lane*4] = acc[rf][c];
  }
  __syncthreads();
  if(wave < 2){
    #pragma unroll
    for(int rf=0;rf<8;rf++)
      #pragma unroll
      for(int c=0;c<CF;c++)
        acc[rf][c] += *(const f32x4*)&red[((wave*SLOT) + rf*CF + c)*256 + lane*4];
  }
  __syncthreads();
  if(wave < 2){
    #pragma unroll
    for(int rf=0;rf<8;rf++)
      #pragma unroll
      for(int c=0;c<CF;c++)
        *(f32x4*)&red[((wave*SLOT) + rf*CF + c)*256 + lane*4] = acc[rf][c];
  }
  __syncthreads();
  const int tpr = 4*CF;          // threads per row (4 cols each)
  const int rpp = 256/tpr;       // rows per pass
  #pragma unroll
  for(int i=0;i<128/rpp;i++){
    int r = tid/tpr + rpp*i;
    int col0 = (tid%tpr)*4;
    int rf = r>>4, rr = r&15, q = rr>>2, g = rr&3;
    f32x4 v;
    #pragma unroll
    for(int j=0;j<4;j++){
      int col = col0+j; int c = col>>4, lo2 = col&15;
      int lane2 = q*16+lo2;
      v[j] = red[(rf*CF + c)*256 + lane2*4 + g]
           + red[(SLOT + rf*CF + c)*256 + lane2*4 + g];
    }
    *(f32x4*)(Cdst + (size_t)r*ldc + col0) = v;
  }
}

// ---- step_in (group-local): input MLP (K=44) + LN + elu -> A2; masked deter ----
__device__ inline void stepin_dev(int b, int t, const float* stochLDS, bool zero,
    const void* action, const void* isf, int enc, int dt,
    const float* paramF, const bf16* W1B,
    const float* deter, float* determ, bf16* A2, float* lds, int tid)
{
  float* in44 = lds;         // 48
  float* sm   = lds + 64;    // 8
  float m = maskv(isf, enc, b*T_ + t);
  if(tid < 32) in44[tid] = zero ? 0.f : stochLDS[tid]*m;
  else if(tid < 44){
    int i = (b*T_+t)*ACT_ + (tid-32);
    float av = dt ? bf2f(((const bf16*)action)[i]) : ((const float*)action)[i];
    in44[tid] = av*m;
  }
  __syncthreads();
  float z[4]; float s=0.f, s2=0.f;
  #pragma unroll
  for(int i=0;i<4;i++){
    int h = tid + 256*i;
    float acc = paramF[Pb1 + h];
    for(int k=0;k<44;k++) acc += in44[k]*bf2f(W1B[k*HID_ + h]);
    z[i]=acc; s+=acc; s2+=acc*acc;
  }
  block_reduce2(s, s2, sm, tid);
  float mean = s/HID_, var = s2/HID_ - mean*mean;
  float rstd = rsqrtf(fmaxf(var,0.f) + 1e-5f);
  #pragma unroll
  for(int i=0;i<4;i++){
    int h = tid + 256*i;
    float xv = (z[i]-mean)*rstd*paramF[Pg1+h] + paramF[Pbn1+h];
    A2[(size_t)b*GRUK_ + h] = f2bf(elu_(xv));
    float dm = zero ? 0.f : deter[b*DETER_+h]*m;
    determ[b*DETER_+h] = dm;
    A2[(size_t)b*GRUK_ + HID_ + h] = f2bf(dm);
  }
}

// ---- GRU (group-local): reduce 4 z2 parts + bias, LN over 3072, gates ----
__device__ inline void gru_dev(int b, int t, const float* z2p, const float* paramF, int dt,
    const float* determ, float* deter, bf16* deterB, void* out, float* lds, int tid)
{
  float* sm = lds;
  float zz[12]; float s=0.f, s2=0.f;
  #pragma unroll
  for(int i=0;i<12;i++){
    int h = tid + 256*i;
    float acc = paramF[Pbg + h];
    #pragma unroll
    for(int p=0;p<4;p++) acc += z2p[((size_t)p*B_ + b)*GRUN_ + h];
    zz[i]=acc; s+=acc; s2+=acc*acc;
  }
  block_reduce2(s, s2, sm, tid);
  float mean = s/GRUN_, var = s2/GRUN_ - mean*mean;
  float rstd = rsqrtf(fmaxf(var,0.f) + 1e-5f);
  #pragma unroll
  for(int j=0;j<4;j++){
    int h0 = tid + 256*j;
    float lnr = (zz[j]   - mean)*rstd*paramF[Pgg+h0     ] + paramF[Pbng+h0     ];
    float lnc = (zz[j+4] - mean)*rstd*paramF[Pgg+h0+1024] + paramF[Pbng+h0+1024];
    float lnu = (zz[j+8] - mean)*rstd*paramF[Pgg+h0+2048] + paramF[Pbng+h0+2048];
    float reset = sigm_(lnr);
    float cand  = tanhf(reset*lnc);
    float upd   = sigm_(lnu - 1.f);          // UPDATE_BIAS
    float dn = upd*cand + (1.f-upd)*determ[b*DETER_+h0];
    deter[b*DETER_+h0]  = dn;
    deterB[b*DETER_+h0] = f2bf(dn);
    stout(out, dt, ((size_t)b*T_+t)*OUTW_ + 192 + h0, dn);
  }
}

// ---- tail (group-local): z3/z5 reduce + LN + elu, dist matmuls, outputs, step_in(t+1) ----
__device__ inline void tail_dev(int b, int t, int idx,
    const float* z3p, const float* z5dp, const float* z5ep,
    const float* paramF, const bf16* W4B, const bf16* W6B, const bf16* W1B,
    int dt, int enc, const void* action, const void* isf,
    const float* deter, float* determ, bf16* A2, void* out, float* lds, int tid)
{
  float* hs  = lds;            // 1024
  float* xo  = lds + 1024;     // 1024
  float* red = lds + 2048;     // 256
  float* dsO = lds + 2304;     // 128
  float* sm  = lds + 2432;     // 8
  float z3v[4], z5v[4]; float s3=0.f,q3=0.f,s5=0.f,q5=0.f;
  #pragma unroll
  for(int i=0;i<4;i++){
    int h = tid + 256*i;
    float a3 = paramF[Pb3 + idx*HID_ + h];
    #pragma unroll
    for(int p=0;p<4;p++) a3 += z3p[((size_t)p*B_+b)*HID_ + h];
    z3v[i]=a3; s3+=a3; q3+=a3*a3;
    float a5 = paramF[Pb5 + h];
    #pragma unroll
    for(int p=0;p<4;p++) a5 += z5dp[((size_t)p*B_+b)*HID_ + h];
    #pragma unroll
    for(int p=0;p<2;p++) a5 += z5ep[((size_t)p*B_+b)*HID_ + h];
    z5v[i]=a5; s5+=a5; q5+=a5*a5;
  }
  block_reduce2(s3, q3, sm, tid);
  block_reduce2(s5, q5, sm, tid);
  float m3=s3/HID_, v3=q3/HID_-m3*m3, r3=rsqrtf(fmaxf(v3,0.f)+1e-5f);
  float m5=s5/HID_, v5=q5/HID_-m5*m5, r5=rsqrtf(fmaxf(v5,0.f)+1e-5f);
  #pragma unroll
  for(int i=0;i<4;i++){
    int h = tid + 256*i;
    hs[h] = elu_((z3v[i]-m3)*r3*paramF[Pg3+idx*HID_+h] + paramF[Pbn3+idx*HID_+h]);
    xo[h] = elu_((z5v[i]-m5)*r5*paramF[Pg5+h] + paramF[Pbn5+h]);
  }
  __syncthreads();
  int j = tid & 63, cch = tid >> 6;
  {
    const bf16* W = W4B + (size_t)idx*HID_*64;
    float a = 0.f;
    for(int k=cch*256; k<cch*256+256; k++) a += hs[k]*bf2f(W[k*64 + j]);
    red[tid] = a;
    __syncthreads();
    if(tid < 64) dsO[tid] = red[tid]+red[tid+64]+red[tid+128]+red[tid+192] + paramF[Pb4+idx*64+tid];
    __syncthreads();
    a = 0.f;
    for(int k=cch*256; k<cch*256+256; k++) a += xo[k]*bf2f(W6B[k*64 + j]);
    red[tid] = a;
    __syncthreads();
    if(tid < 64) dsO[64+tid] = red[tid]+red[tid+64]+red[tid+128]+red[tid+192] + paramF[Pb6+tid];
    __syncthreads();
  }
  size_t ob = ((size_t)b*T_ + t)*OUTW_;
  if(tid < 32){
    float pm = dsO[tid];
    float ps = softplus_(dsO[32+tid]) + 0.1f;
    float om = dsO[64+tid];
    float os = softplus_(dsO[96+tid]) + 0.1f;
    stout(out, dt, ob+tid,      om);   // omean
    stout(out, dt, ob+32+tid,   os);   // ostd
    stout(out, dt, ob+64+tid,   om);   // post_stoch
    stout(out, dt, ob+96+tid,   pm);   // pmean
    stout(out, dt, ob+128+tid,  ps);   // pstd
    stout(out, dt, ob+160+tid,  pm);   // prior_stoch
  }
  if(t+1 < T_)
    stepin_dev(b, t+1, dsO+64, false, action, isf, enc, dt, paramF, W1B,
               deter, determ, A2, lds + 2560, tid);
}

// ---- persistent scan kernel: 256 blocks x 512 threads (2 groups), 4 barriers/step ----
__global__ __launch_bounds__(512) void k_persist(
    const void* action, const void* isf, const int* dflag, const float* paramF,
    const bf16* W1B, const bf16* W4B, const bf16* W6B,
    const bf16* embB, const bf16* WgT, const bf16* W3T, const bf16* W5T,
    bf16* A2, bf16* deterB, float* deter, float* determ,
    float* z2p, float* z3p, float* z5dp, float* z5ep,
    void* out, const int* ens_index, int* cnt)
{
  __shared__ float lds[16384];   // 64 KB: 2 x 32 KB group scratch
  int g = threadIdx.x >> 8;
  int tid = threadIdx.x & 255;
  float* gl = lds + g*8192;
  int bid = blockIdx.x;
  int u = bid*2 + g;
  int dt = dflag[0], enc = dflag[1];
  int ep = 0;

  // init: step_in(t=0) with zero carry (units 0..127)
  if(bid < 64)
    stepin_dev(u, 0, nullptr, true, action, isf, enc, dt, paramF, W1B,
               nullptr, determ, A2, gl, tid);
  gbar(cnt, ep);

  for(int t=0; t<T_; t++){
    int idx = ens_index[t];
    // ---- G1: GRU GEMM (units 0..383, 96 ct x 4 parts) + z5 embed part (units 384..511) ----
    if(bid < 192){
      int ct = u % 96, part = u / 96;
      gemm_tile<2>(A2, GRUK_,
                   WgT + (size_t)ct*32*GRUK_, GRUK_,
                   z2p + (size_t)part*B_*GRUN_ + ct*32, GRUN_,
                   part*512, 512, gl, tid);
    } else {
      int e = u - 384; int ct = e & 63, part = e >> 6;
      gemm_tile<1>(embB + (size_t)t*EMB_, T_*EMB_,
                   W5T + (size_t)ct*16*OBSK_ + 1024, OBSK_,
                   z5ep + (size_t)part*B_*HID_ + ct*16, HID_,
                   part*768, 768, gl, tid);
    }
    gbar(cnt, ep);
    // ---- GRU (units 0..127) ----
    if(bid < 64)
      gru_dev(u, t, z2p, paramF, dt, determ, deter, deterB, out, gl, tid);
    gbar(cnt, ep);
    // ---- G2: z3 (units 0..255, 64 ct x 4 parts) + z5 deter part (units 256..511) ----
    if(bid < 128){
      int ct = u & 63, part = u >> 6;
      gemm_tile<1>(deterB, DETER_,
                   W3T + (size_t)idx*DETER_*HID_ + (size_t)ct*16*DETER_, DETER_,
                   z3p + (size_t)part*B_*HID_ + ct*16, HID_,
                   part*256, 256, gl, tid);
    } else {
      int e = u - 256; int ct = e & 63, part = e >> 6;
      gemm_tile<1>(deterB, DETER_,
                   W5T + (size_t)ct*16*OBSK_, OBSK_,
                   z5dp + (size_t)part*B_*HID_ + ct*16, HID_,
                   part*256, 256, gl, tid);
    }
    gbar(cnt, ep);
    // ---- TAIL (units 0..127): heads + outputs + step_in(t+1) ----
    if(bid < 64)
      tail_dev(u, t, idx, z3p, z5dp, z5ep, paramF, W4B, W6B, W1B,
               dt, enc, action, isf, deter, determ, A2, out, gl, tid);
    gbar(cnt, ep);
  }
}

extern "C" void kernel_launch(void* const* d_in, const int* in_sizes, int n_in,
                              void* d_out, int out_size, void* d_ws, size_t ws_size,
                              hipStream_t stream)
{
  const void* embed  = d_in[0];
  const void* action = d_in[1];
  const void* isf    = d_in[2];
  const int*  ens_ix = (const int*)d_in[3];

  char* ws = (char*)d_ws;
  float* deter  = (float*)(ws + 0);            // 512 KB
  float* determ = (float*)(ws + 524288);       // 512 KB
  bf16*  A2     = (bf16*) (ws + 1048576);      // 512 KB
  bf16*  deterB = (bf16*) (ws + 1572864);      // 256 KB
  float* z2p    = (float*)(ws + 1835008);      // 6 MB (4 parts)
  float* z3p    = (float*)(ws + 8126464);      // 2 MB (4 parts)
  float* z5dp   = (float*)(ws + 10223616);     // 2 MB (4 parts)
  float* z5ep   = (float*)(ws + 12320768);     // 1 MB (2 parts)
  bf16*  WgT    = (bf16*) (ws + 13369344);     // 12.6 MB
  bf16*  W3T    = (bf16*) (ws + 25952256);     // 10.5 MB
  bf16*  W5T    = (bf16*) (ws + 36438016);     // 5.2 MB
  float* paramF = (float*)(ws + 41680896);     // 0.30 MB
  bf16*  embB   = (bf16*) (ws + 41985536);     // 25.2 MB
  bf16*  W1B    = (bf16*) (ws + 67151360);     // 88 KB
  bf16*  W4B    = (bf16*) (ws + 67241472);     // 640 KB
  bf16*  W6B    = (bf16*) (ws + 67896832);     // 128 KB
  int*   dflag  = (int*)  (ws + 68027904);
  int*   cnt    = (int*)  (ws + 68027968);

  k_detect_dtype<<<1,256,0,stream>>>((const unsigned short*)embed, dflag);
  k_detect_isf<<<1,256,0,stream>>>((const unsigned char*)isf, dflag);
  k_zero_i<<<1,64,0,stream>>>(cnt);

  PDesc pd;
  const int srcidx[15] = {4,5,6,7, 9,10,11, 13,14,15, 17, 19,20,21, 23};
  const int sizes[15]  = {45056,1024,1024,1024, 3072,3072,3072, 5120,5120,5120,
                          320, 1024,1024,1024, 64};
  int cum = 0;
  for(int i=0;i<15;i++){ pd.src[i] = d_in[srcidx[i]]; pd.cum[i] = cum; cum += sizes[i]; }
  pd.cum[15] = cum;  // 76160
  k_params<<<(PTOT+255)/256, 256, 0, stream>>>(pd, paramF, dflag);

  k_cvt_bf<<<(B_*T_*EMB_)/1024, 256, 0, stream>>>(embed, embB, B_*T_*EMB_, dflag);
  k_cvt_bf<<<44, 256, 0, stream>>>(d_in[4],  W1B, 44*HID_, dflag);
  k_cvt_bf<<<320,256, 0, stream>>>(d_in[16], W4B, 5*HID_*64, dflag);
  k_cvt_bf<<<64, 256, 0, stream>>>(d_in[22], W6B, HID_*64, dflag);

  k_transpose<<<dim3((GRUK_/64)*(GRUN_/64),1), 256, 0, stream>>>(d_in[8],  WgT, GRUK_, GRUN_, dflag);
  k_transpose<<<dim3((DETER_/64)*(HID_/64),5), 256, 0, stream>>>(d_in[12], W3T, DETER_, HID_, dflag);
  k_transpose<<<dim3((OBSK_/64)*(HID_/64),1), 256, 0, stream>>>(d_in[18], W5T, OBSK_, HID_, dflag);

  k_persist<<<256,512,0,stream>>>(action, isf, dflag, paramF, W1B, W4B, W6B,
                                  embB, WgT, W3T, W5T,
                                  A2, deterB, deter, determ,
                                  z2p, z3p, z5dp, z5ep,
                                  d_out, ens_ix, cnt);
}

// Round 7
// 19737.184 us; speedup vs baseline: 3.2781x; 1.0598x over previous
//
#include <hip/hip_runtime.h>
#include <hip/hip_bf16.h>
#include <math.h>

using bf16 = __hip_bfloat16;
using short8 = __attribute__((ext_vector_type(8))) short;
using short4v = __attribute__((ext_vector_type(4))) short;
using f32x4  = __attribute__((ext_vector_type(4))) float;
using int2v  = __attribute__((ext_vector_type(2))) int;

#define B_     128
#define T_     64
#define EMB_   1536
#define ACT_   12
#define STOCH_ 32
#define DETER_ 1024
#define HID_   1024
#define GRUN_  3072
#define GRUK_  2048
#define OBSK_  2560
#define OUTW_  1216   // 6*STOCH + DETER

// canonical f32 param block offsets (floats)
#define Pb1   45056
#define Pg1   46080
#define Pbn1  47104
#define Pbg   48128
#define Pgg   51200
#define Pbng  54272
#define Pb3   57344
#define Pg3   62464
#define Pbn3  67584
#define Pb4   72704
#define Pb5   73024
#define Pg5   74048
#define Pbn5  75072
#define Pb6   76096
#define PTOT  76160

#define LDSROW 152   // bf16 row stride in LDS staging (76 dwords: 2-way-conflict free, 16B aligned)

__device__ inline float bf2f(bf16 v){ return __bfloat162float(v); }
__device__ inline bf16  f2bf(float v){ return __float2bfloat16(v); }
__device__ inline float bfbits2f(unsigned short u){
  return __uint_as_float(((unsigned int)u) << 16);
}
__device__ inline float elu_(float x){ return x > 0.f ? x : expm1f(x); }
__device__ inline float sigm_(float x){ return 1.f/(1.f+expf(-x)); }
__device__ inline float softplus_(float x){ return fmaxf(x,0.f) + log1pf(expf(-fabsf(x))); }
__device__ inline void stout(void* out, int dt, size_t i, float v){
  if(dt) ((bf16*)out)[i] = f2bf(v); else ((float*)out)[i] = v;
}
__device__ inline float maskv(const void* isf, int enc, int idx){
  float fv;
  if(enc==0)      fv = (float)((const int*)isf)[idx];
  else if(enc==1) fv = (float)((const unsigned char*)isf)[idx];
  else if(enc==2) fv = bf2f(((const bf16*)isf)[idx]);
  else            fv = ((const float*)isf)[idx];
  return (fv != 0.f) ? 0.f : 1.f;
}

// ---------------- sc0 sc1 (coherent, cache-bypass) access helpers ----------------
__device__ inline void ldg4_cv(f32x4& a, f32x4& b, f32x4& c, f32x4& d,
    const float* p0, const float* p1, const float* p2, const float* p3){
  asm volatile(
    "global_load_dwordx4 %0, %4, off sc0 sc1\n\t"
    "global_load_dwordx4 %1, %5, off sc0 sc1\n\t"
    "global_load_dwordx4 %2, %6, off sc0 sc1\n\t"
    "global_load_dwordx4 %3, %7, off sc0 sc1\n\t"
    "s_waitcnt vmcnt(0)"
    : "=v"(a),"=v"(b),"=v"(c),"=v"(d)
    : "v"(p0),"v"(p1),"v"(p2),"v"(p3)
    : "memory");
}
__device__ inline void stg_f(float* p, float v){
  asm volatile("global_store_dword %0, %1, off sc0 sc1" :: "v"(p), "v"(v) : "memory");
}
__device__ inline void stg_b16(bf16* p, float v){
  bf16 h = f2bf(v);
  unsigned int d = *(unsigned short*)&h;
  asm volatile("global_store_short %0, %1, off sc0 sc1" :: "v"(p), "v"(d) : "memory");
}
__device__ inline void stg_b16x4(bf16* p, float a0, float a1, float a2, float a3){
  bf16 h0=f2bf(a0),h1=f2bf(a1),h2=f2bf(a2),h3=f2bf(a3);
  int2v d;
  d[0] = (int)((*(unsigned short*)&h0) | ((unsigned int)(*(unsigned short*)&h1)<<16));
  d[1] = (int)((*(unsigned short*)&h2) | ((unsigned int)(*(unsigned short*)&h3)<<16));
  asm volatile("global_store_dwordx2 %0, %1, off sc0 sc1" :: "v"(p), "v"(d) : "memory");
}

// stage 64 rows x 128 k (bf16) from global (bypass) into LDS [row][LDSROW]
__device__ inline void stage64(const bf16* gbase, int gstride, bf16* sh, int tid){
  short8 v0,v1,v2,v3;
  const bf16 *p0,*p1,*p2,*p3;
  {
    int i0=tid, i1=tid+256, i2=tid+512, i3=tid+768;
    p0 = gbase + (size_t)(i0>>4)*gstride + (i0&15)*8;
    p1 = gbase + (size_t)(i1>>4)*gstride + (i1&15)*8;
    p2 = gbase + (size_t)(i2>>4)*gstride + (i2&15)*8;
    p3 = gbase + (size_t)(i3>>4)*gstride + (i3&15)*8;
  }
  asm volatile(
    "global_load_dwordx4 %0, %4, off sc0 sc1\n\t"
    "global_load_dwordx4 %1, %5, off sc0 sc1\n\t"
    "global_load_dwordx4 %2, %6, off sc0 sc1\n\t"
    "global_load_dwordx4 %3, %7, off sc0 sc1\n\t"
    "s_waitcnt vmcnt(0)"
    : "=v"(v0),"=v"(v1),"=v"(v2),"=v"(v3)
    : "v"(p0),"v"(p1),"v"(p2),"v"(p3)
    : "memory");
  *(short8*)(sh + (tid>>4)*LDSROW        + (tid&15)*8) = v0;
  *(short8*)(sh + ((tid+256)>>4)*LDSROW + (tid&15)*8) = v1;
  *(short8*)(sh + ((tid+512)>>4)*LDSROW + (tid&15)*8) = v2;
  *(short8*)(sh + ((tid+768)>>4)*LDSROW + (tid&15)*8) = v3;
}

// group-local (4-wave, tid=0..255) reduction of two values
__device__ inline void block_reduce2(float& a, float& b, float* sm, int tid){
  __syncthreads();
  for(int off=32; off>0; off>>=1){
    a += __shfl_down(a, off);
    b += __shfl_down(b, off);
  }
  int w = tid >> 6;
  if((tid & 63) == 0){ sm[2*w] = a; sm[2*w+1] = b; }
  __syncthreads();
  a = sm[0]+sm[2]+sm[4]+sm[6];
  b = sm[1]+sm[3]+sm[5]+sm[7];
}

// ---- fence-free grid barrier: 8 spread arrive counters + broadcast flag ----
__device__ inline void gbar(int* cnt, int& ep, int bid){
  __syncthreads();
  ep++;
  if(threadIdx.x == 0){
    asm volatile("s_waitcnt vmcnt(0) lgkmcnt(0)" ::: "memory");
    __hip_atomic_fetch_add(&cnt[(bid&7)*32], 1, __ATOMIC_RELAXED, __HIP_MEMORY_SCOPE_AGENT);
    if(bid == 0){
      for(;;){
        int s = 0;
        #pragma unroll
        for(int i=0;i<8;i++)
          s += __hip_atomic_load(&cnt[i*32], __ATOMIC_RELAXED, __HIP_MEMORY_SCOPE_AGENT);
        if(s >= ep*256) break;
        __builtin_amdgcn_s_sleep(1);
      }
      __hip_atomic_store(&cnt[256], ep, __ATOMIC_RELAXED, __HIP_MEMORY_SCOPE_AGENT);
    } else {
      while(__hip_atomic_load(&cnt[256], __ATOMIC_RELAXED, __HIP_MEMORY_SCOPE_AGENT) < ep)
        __builtin_amdgcn_s_sleep(1);
    }
  }
  __syncthreads();
}

// ---------------- prep kernels ----------------
__global__ void k_detect_dtype(const unsigned short* emb, int* dflag){
  __shared__ int cnt;
  if(threadIdx.x==0) cnt = 0;
  __syncthreads();
  int c = 0;
  for(int i=threadIdx.x; i<2048; i+=256){
    unsigned short u = emb[2*i];
    int exp8 = (u >> 7) & 0xFF;
    if(exp8 > 140) c++;
  }
  atomicAdd(&cnt, c);
  __syncthreads();
  if(threadIdx.x==0) dflag[0] = (cnt < 100) ? 1 : 0;
}

__global__ void k_detect_isf(const unsigned char* isf, int* dflag){
  __shared__ int f_bf, f_f32, f_u8;
  if(threadIdx.x==0){ f_bf=0; f_f32=0; f_u8=0; }
  __syncthreads();
  for(int i=threadIdx.x; i<B_*T_; i+=256){
    unsigned char c = isf[i];
    if(c == 0x3F){
      if((i & 3) == 1) atomicOr(&f_bf, 1);
      else if((i & 3) == 3) atomicOr(&f_f32, 1);
    }
    if(c == 1 && (i & 3) != 0) atomicOr(&f_u8, 1);
  }
  __syncthreads();
  if(threadIdx.x==0)
    dflag[1] = f_bf ? 2 : (f_f32 ? 3 : (f_u8 ? 1 : 0));
}

__global__ void k_zero_i(int* p){
  p[threadIdx.x] = 0;
}

struct PDesc { const void* src[15]; int cum[16]; };
__global__ __launch_bounds__(256) void k_params(PDesc pd, float* dst, const int* dflag){
  int g = blockIdx.x*256 + threadIdx.x;
  if(g >= PTOT) return;
  int dt = dflag[0];
  int s = 0;
  while(g >= pd.cum[s+1]) s++;
  int off = g - pd.cum[s];
  dst[g] = dt ? bf2f(((const bf16*)pd.src[s])[off]) : ((const float*)pd.src[s])[off];
}

__global__ void k_cvt_bf(const void* src, bf16* dst, int n, const int* dflag){
  int dt = dflag[0];
  int i0 = (blockIdx.x*256 + threadIdx.x)*4;
  #pragma unroll
  for(int k=0;k<4;k++){
    int i = i0+k;
    if(i < n) dst[i] = dt ? ((const bf16*)src)[i] : f2bf(((const float*)src)[i]);
  }
}

__global__ __launch_bounds__(256) void k_transpose(const void* src, bf16* dst, int K, int N, const int* dflag){
  __shared__ unsigned short t[64][72];
  int dt = dflag[0];
  int tilesN = N/64;
  int tk = blockIdx.x / tilesN, tn = blockIdx.x % tilesN;
  size_t hoff = (size_t)blockIdx.y * K * N;
  unsigned short* d = (unsigned short*)dst + hoff;
  int tx = threadIdx.x & 63, ty0 = threadIdx.x >> 6;
  int k0 = tk*64, n0 = tn*64;
  #pragma unroll
  for(int i=0;i<16;i++){
    int ty = ty0*16+i;
    size_t off = hoff + (size_t)(k0+ty)*N + n0+tx;
    unsigned short v;
    if(dt) v = ((const unsigned short*)src)[off];
    else { bf16 b = f2bf(((const float*)src)[off]); v = *(unsigned short*)&b; }
    t[ty][tx] = v;
  }
  __syncthreads();
  #pragma unroll
  for(int i=0;i<16;i++){ int ty = ty0*16+i; d[(size_t)(n0+ty)*K + k0+tx] = t[tx][ty]; }
}

// ---- precompute z5e[bt][1024] (bf16) = embed @ W_obs[1024:,:] ; state-independent ----
__global__ __launch_bounds__(256) void k_z5e(const void* embed, const bf16* W5T,
                                             bf16* z5eB, const int* dflag){
  int dt = dflag[0];
  int bid = blockIdx.x;
  int mt = bid & 127, ct = bid >> 7;
  int tid = threadIdx.x, w = tid>>6, lane = tid&63, quad = lane>>4, lo = lane&15;
  int r = mt*64 + 16*w + lo;
  f32x4 acc[8];
  #pragma unroll
  for(int c=0;c<8;c++) acc[c] = (f32x4)0.f;
  for(int k=0;k<EMB_;k+=32){
    int kf = k + quad*8;
    short8 a;
    if(dt){
      a = *(const short8*)((const bf16*)embed + (size_t)r*EMB_ + kf);
    } else {
      const float* pf = (const float*)embed + (size_t)r*EMB_ + kf;
      #pragma unroll
      for(int j=0;j<8;j++){ bf16 h = f2bf(pf[j]); a[j] = *(short*)&h; }
    }
    #pragma unroll
    for(int c=0;c<8;c++){
      short8 b = *(const short8*)(W5T + (size_t)(ct*128+16*c+lo)*OBSK_ + 1024 + kf);
      acc[c] = __builtin_amdgcn_mfma_f32_16x16x32_bf16(a, b, acc[c], 0,0,0);
    }
  }
  #pragma unroll
  for(int c=0;c<8;c++)
    #pragma unroll
    for(int gg=0;gg<4;gg++)
      z5eB[(size_t)(mt*64+16*w+quad*4+gg)*HID_ + ct*128+16*c+lo] = f2bf(acc[c][gg]);
}

// ---------------- persistent-kernel device phases ----------------

// GEMM unit (4-wave group): 64 rows x 128 cols, wave w owns rows 16w..16w+15 over full Kslice.
// A staged from bypass global into LDS in 128-k chunks; B cached; C stored bypass f32.
template<int KCHUNKS>
__device__ inline void gemm_unit(const bf16* Abase, int astride,
                                 const bf16* Bcol, int ldb,
                                 float* Cbase, int ldc,
                                 bf16* shA, int tid)
{
  int w = tid>>6, lane = tid&63, quad = lane>>4, lo = lane&15;
  f32x4 acc[8];
  #pragma unroll
  for(int c=0;c<8;c++) acc[c] = (f32x4)0.f;
  for(int ch=0; ch<KCHUNKS; ch++){
    int k0 = ch*128;
    __syncthreads();
    stage64(Abase + k0, astride, shA, tid);
    __syncthreads();
    #pragma unroll
    for(int ki=0; ki<4; ki++){
      int kf = ki*32 + quad*8;
      short8 a = *(const short8*)(shA + (16*w+lo)*LDSROW + kf);
      #pragma unroll
      for(int c=0;c<8;c++){
        short8 b = *(const short8*)(Bcol + (size_t)(16*c+lo)*ldb + k0 + kf);
        acc[c] = __builtin_amdgcn_mfma_f32_16x16x32_bf16(a, b, acc[c], 0,0,0);
      }
    }
  }
  #pragma unroll
  for(int c=0;c<8;c++)
    #pragma unroll
    for(int gg=0;gg<4;gg++){
      float* p = Cbase + (size_t)(16*w + quad*4 + gg)*ldc + 16*c + lo;
      stg_f(p, acc[c][gg]);
    }
}

// step_in: input MLP (K=44) + LN + elu -> A2[b][0:1024] (bypass); masked deter -> determ, A2[b][1024:2048]
__device__ inline void stepin_dev(int b, int t, const float* stochLDS, bool zero,
    const void* action, const void* isf, int enc, int dt,
    const float* paramF, const bf16* W1B,
    const float* deter, float* determ, bf16* A2, float* lds, int tid)
{
  float* in44 = lds;         // 48
  float* sm   = lds + 64;    // 8
  float m = maskv(isf, enc, b*T_ + t);
  if(tid < 32) in44[tid] = zero ? 0.f : stochLDS[tid]*m;
  else if(tid < 44){
    int i = (b*T_+t)*ACT_ + (tid-32);
    float av = dt ? bf2f(((const bf16*)action)[i]) : ((const float*)action)[i];
    in44[tid] = av*m;
  }
  __syncthreads();
  float z[4]; float s=0.f, s2=0.f;
  #pragma unroll
  for(int i=0;i<4;i++){
    int h = tid + 256*i;
    float acc = paramF[Pb1 + h];
    for(int k=0;k<44;k++) acc += in44[k]*bf2f(W1B[k*HID_ + h]);
    z[i]=acc; s+=acc; s2+=acc*acc;
  }
  block_reduce2(s, s2, sm, tid);
  float mean = s/HID_, var = s2/HID_ - mean*mean;
  float rstd = rsqrtf(fmaxf(var,0.f) + 1e-5f);
  #pragma unroll
  for(int i=0;i<4;i++){
    int h = tid + 256*i;
    float xv = (z[i]-mean)*rstd*paramF[Pg1+h] + paramF[Pbn1+h];
    stg_b16(A2 + (size_t)b*GRUK_ + h, elu_(xv));
    float dm = zero ? 0.f : deter[b*DETER_+h]*m;
    determ[b*DETER_+h] = dm;
    stg_b16(A2 + (size_t)b*GRUK_ + HID_ + h, dm);
  }
}

// GRU: reduce 4 z2 parts + bias, LN over 3072, gates -> deter (cached) / deterB (bypass) / out
__device__ inline void gru_dev(int b, int t, const float* z2p, const float* paramF, int dt,
    const float* determ, float* deter, bf16* deterB, void* out, float* lds, int tid)
{
  float* sm = lds;
  float zz[3][4]; float s=0.f, s2=0.f;
  #pragma unroll
  for(int j=0;j<3;j++){
    f32x4 q0,q1,q2,q3;
    const float* base = z2p + (size_t)b*GRUN_ + j*1024 + 4*tid;
    ldg4_cv(q0,q1,q2,q3, base, base + (size_t)B_*GRUN_, base + (size_t)2*B_*GRUN_, base + (size_t)3*B_*GRUN_);
    f32x4 bias = *(const f32x4*)(paramF + Pbg + j*1024 + 4*tid);
    #pragma unroll
    for(int e=0;e<4;e++){
      float a = bias[e] + q0[e] + q1[e] + q2[e] + q3[e];
      zz[j][e] = a; s += a; s2 += a*a;
    }
  }
  block_reduce2(s, s2, sm, tid);
  float mean = s/GRUN_, var = s2/GRUN_ - mean*mean;
  float rstd = rsqrtf(fmaxf(var,0.f) + 1e-5f);
  f32x4 gr = *(const f32x4*)(paramF + Pgg + 4*tid);
  f32x4 gc = *(const f32x4*)(paramF + Pgg + 1024 + 4*tid);
  f32x4 gu = *(const f32x4*)(paramF + Pgg + 2048 + 4*tid);
  f32x4 br = *(const f32x4*)(paramF + Pbng + 4*tid);
  f32x4 bc = *(const f32x4*)(paramF + Pbng + 1024 + 4*tid);
  f32x4 bu = *(const f32x4*)(paramF + Pbng + 2048 + 4*tid);
  f32x4 dm = *(const f32x4*)(determ + (size_t)b*DETER_ + 4*tid);
  float dn[4];
  #pragma unroll
  for(int e=0;e<4;e++){
    float lnr = (zz[0][e]-mean)*rstd*gr[e] + br[e];
    float lnc = (zz[1][e]-mean)*rstd*gc[e] + bc[e];
    float lnu = (zz[2][e]-mean)*rstd*gu[e] + bu[e];
    float reset = sigm_(lnr);
    float cand  = tanhf(reset*lnc);
    float upd   = sigm_(lnu - 1.f);
    dn[e] = upd*cand + (1.f-upd)*dm[e];
    stout(out, dt, ((size_t)b*T_+t)*OUTW_ + 192 + 4*tid + e, dn[e]);
  }
  f32x4 dv; dv[0]=dn[0]; dv[1]=dn[1]; dv[2]=dn[2]; dv[3]=dn[3];
  *(f32x4*)(deter + (size_t)b*DETER_ + 4*tid) = dv;
  stg_b16x4(deterB + (size_t)b*DETER_ + 4*tid, dn[0],dn[1],dn[2],dn[3]);
}

// TAIL: reduce z3/z5 parts + z5e, LN+elu, dist matmuls, outputs, fused step_in(t+1)
__device__ inline void tail_dev(int b, int t, int idx,
    const float* z3p, const float* z5dp, const bf16* z5eB,
    const float* paramF, const bf16* W4B, const bf16* W6B, const bf16* W1B,
    int dt, int enc, const void* action, const void* isf,
    const float* deter, float* determ, bf16* A2, void* out, float* lds, int tid)
{
  float* hs  = lds;            // 1024
  float* xo  = lds + 1024;     // 1024
  float* red = lds + 2048;     // 256
  float* dsO = lds + 2304;     // 128
  float* sm  = lds + 2432;     // 8
  float s3=0.f,q3=0.f,s5=0.f,q5=0.f;
  float z3v[4], z5v[4];
  {
    f32x4 a0,a1,a2,a3;
    const float* base3 = z3p + (size_t)b*HID_ + 4*tid;
    ldg4_cv(a0,a1,a2,a3, base3, base3 + (size_t)B_*HID_, base3 + (size_t)2*B_*HID_, base3 + (size_t)3*B_*HID_);
    f32x4 b3v = *(const f32x4*)(paramF + Pb3 + idx*HID_ + 4*tid);
    #pragma unroll
    for(int e=0;e<4;e++){
      float a = b3v[e] + a0[e]+a1[e]+a2[e]+a3[e];
      z3v[e]=a; s3+=a; q3+=a*a;
    }
    const float* base5 = z5dp + (size_t)b*HID_ + 4*tid;
    ldg4_cv(a0,a1,a2,a3, base5, base5 + (size_t)B_*HID_, base5 + (size_t)2*B_*HID_, base5 + (size_t)3*B_*HID_);
    f32x4 b5v = *(const f32x4*)(paramF + Pb5 + 4*tid);
    short4v ze = *(const short4v*)(z5eB + (size_t)(b*T_+t)*HID_ + 4*tid);
    #pragma unroll
    for(int e=0;e<4;e++){
      float a = b5v[e] + a0[e]+a1[e]+a2[e]+a3[e] + bfbits2f((unsigned short)ze[e]);
      z5v[e]=a; s5+=a; q5+=a*a;
    }
  }
  block_reduce2(s3, q3, sm, tid);
  block_reduce2(s5, q5, sm, tid);
  float m3=s3/HID_, v3=q3/HID_-m3*m3, r3=rsqrtf(fmaxf(v3,0.f)+1e-5f);
  float m5=s5/HID_, v5=q5/HID_-m5*m5, r5=rsqrtf(fmaxf(v5,0.f)+1e-5f);
  {
    f32x4 hv, xv;
    f32x4 g3v = *(const f32x4*)(paramF + Pg3 + idx*HID_ + 4*tid);
    f32x4 n3v = *(const f32x4*)(paramF + Pbn3 + idx*HID_ + 4*tid);
    f32x4 g5v = *(const f32x4*)(paramF + Pg5 + 4*tid);
    f32x4 n5v = *(const f32x4*)(paramF + Pbn5 + 4*tid);
    #pragma unroll
    for(int e=0;e<4;e++){
      hv[e] = elu_((z3v[e]-m3)*r3*g3v[e] + n3v[e]);
      xv[e] = elu_((z5v[e]-m5)*r5*g5v[e] + n5v[e]);
    }
    *(f32x4*)&hs[4*tid] = hv;
    *(f32x4*)&xo[4*tid] = xv;
  }
  __syncthreads();
  int j = tid & 63, cch = tid >> 6;
  {
    const bf16* W = W4B + (size_t)idx*HID_*64;
    float a = 0.f;
    for(int k=cch*256; k<cch*256+256; k++) a += hs[k]*bf2f(W[k*64 + j]);
    red[tid] = a;
    __syncthreads();
    if(tid < 64) dsO[tid] = red[tid]+red[tid+64]+red[tid+128]+red[tid+192] + paramF[Pb4+idx*64+tid];
    __syncthreads();
    a = 0.f;
    for(int k=cch*256; k<cch*256+256; k++) a += xo[k]*bf2f(W6B[k*64 + j]);
    red[tid] = a;
    __syncthreads();
    if(tid < 64) dsO[64+tid] = red[tid]+red[tid+64]+red[tid+128]+red[tid+192] + paramF[Pb6+tid];
    __syncthreads();
  }
  size_t ob = ((size_t)b*T_ + t)*OUTW_;
  if(tid < 32){
    float pm = dsO[tid];
    float ps = softplus_(dsO[32+tid]) + 0.1f;
    float om = dsO[64+tid];
    float os = softplus_(dsO[96+tid]) + 0.1f;
    stout(out, dt, ob+tid,      om);
    stout(out, dt, ob+32+tid,   os);
    stout(out, dt, ob+64+tid,   om);
    stout(out, dt, ob+96+tid,   pm);
    stout(out, dt, ob+128+tid,  ps);
    stout(out, dt, ob+160+tid,  pm);
  }
  if(t+1 < T_)
    stepin_dev(b, t+1, dsO+64, false, action, isf, enc, dt, paramF, W1B,
               deter, determ, A2, lds + 2440, tid);
}

// ---- persistent scan kernel: 256 blocks x 512 threads (2 groups/block) ----
__global__ __launch_bounds__(512) void k_persist(
    const void* action, const void* isf, const int* dflag, const float* paramF,
    const bf16* W1B, const bf16* W4B, const bf16* W6B,
    const bf16* z5eB, const bf16* WgT, const bf16* W3T, const bf16* W5T,
    bf16* A2, bf16* deterB, float* deter, float* determ,
    float* z2p, float* z3p, float* z5dp,
    void* out, const int* ens_index, int* cnt)
{
  __shared__ bf16  shA[2][64*LDSROW];  // 2 x 19456 B
  __shared__ float shS[2][2688];       // 2 x 10752 B
  int g = threadIdx.x >> 8;
  int tid = threadIdx.x & 255;
  int bid = blockIdx.x;
  int u = 2*bid + g;
  int dt = dflag[0], enc = dflag[1];
  int ep = 0;

  if(bid < 64)
    stepin_dev(u, 0, nullptr, true, action, isf, enc, dt, paramF, W1B,
               nullptr, determ, A2, shS[g] + 2440, tid);
  gbar(cnt, ep, bid);

  for(int t=0; t<T_; t++){
    int idx = ens_index[t];
    // ---- G1: z2 = A2 @ Wg  (192 units: ct 24 x m 2 x kp 4) ----
    if(bid < 96){
      int ct = u % 24;
      int mk = u / 24;
      int m = mk & 1, kp = mk >> 1;
      gemm_unit<4>(A2 + (size_t)(m*64)*GRUK_ + kp*512, GRUK_,
                   WgT + (size_t)(ct*128)*GRUK_ + kp*512, GRUK_,
                   z2p + (size_t)kp*B_*GRUN_ + (size_t)(m*64)*GRUN_ + ct*128, GRUN_,
                   shA[g], tid);
    }
    gbar(cnt, ep, bid);
    // ---- GRU (128 units) ----
    if(bid < 64)
      gru_dev(u, t, z2p, paramF, dt, determ, deter, deterB, out, shS[g], tid);
    gbar(cnt, ep, bid);
    // ---- G2: z3 (64 units) + z5d (64 units); ct 8 x m 2 x kp 4, K=256 ----
    if(bid < 64){
      int e = (u < 64) ? u : (u - 64);
      int ct = e & 7, m = (e >> 3) & 1, kp = e >> 4;
      if(u < 64){
        gemm_unit<2>(deterB + (size_t)(m*64)*DETER_ + kp*256, DETER_,
                     W3T + (size_t)idx*DETER_*HID_ + (size_t)(ct*128)*DETER_ + kp*256, DETER_,
                     z3p + (size_t)kp*B_*HID_ + (size_t)(m*64)*HID_ + ct*128, HID_,
                     shA[g], tid);
      } else {
        gemm_unit<2>(deterB + (size_t)(m*64)*DETER_ + kp*256, DETER_,
                     W5T + (size_t)(ct*128)*OBSK_ + kp*256, OBSK_,
                     z5dp + (size_t)kp*B_*HID_ + (size_t)(m*64)*HID_ + ct*128, HID_,
                     shA[g], tid);
      }
    }
    gbar(cnt, ep, bid);
    // ---- TAIL (128 units): heads + outputs + step_in(t+1) ----
    if(bid < 64)
      tail_dev(u, t, idx, z3p, z5dp, z5eB, paramF, W4B, W6B, W1B,
               dt, enc, action, isf, deter, determ, A2, out, shS[g], tid);
    gbar(cnt, ep, bid);
  }
}

extern "C" void kernel_launch(void* const* d_in, const int* in_sizes, int n_in,
                              void* d_out, int out_size, void* d_ws, size_t ws_size,
                              hipStream_t stream)
{
  const void* embed  = d_in[0];
  const void* action = d_in[1];
  const void* isf    = d_in[2];
  const int*  ens_ix = (const int*)d_in[3];

  char* ws = (char*)d_ws;
  float* deter  = (float*)(ws + 0);            // 512 KB
  float* determ = (float*)(ws + 524288);       // 512 KB
  bf16*  A2     = (bf16*) (ws + 1048576);      // 512 KB
  bf16*  deterB = (bf16*) (ws + 1572864);      // 256 KB
  float* z2p    = (float*)(ws + 1835008);      // 6 MB (4 parts)
  float* z3p    = (float*)(ws + 8126464);      // 2 MB (4 parts)
  float* z5dp   = (float*)(ws + 10223616);     // 2 MB (4 parts)
  bf16*  z5eB   = (bf16*) (ws + 12320768);     // 16.8 MB [8192][1024] bf16
  bf16*  WgT    = (bf16*) (ws + 29097984);     // 12.6 MB
  bf16*  W3T    = (bf16*) (ws + 41680896);     // 10.5 MB
  bf16*  W5T    = (bf16*) (ws + 52166656);     // 5.2 MB
  float* paramF = (float*)(ws + 57409536);     // 0.30 MB
  bf16*  W1B    = (bf16*) (ws + 57714176);     // 88 KB
  bf16*  W4B    = (bf16*) (ws + 57804288);     // 640 KB
  bf16*  W6B    = (bf16*) (ws + 58459648);     // 128 KB
  int*   dflag  = (int*)  (ws + 58590720);
  int*   cnt    = (int*)  (ws + 58591232);     // 512 ints

  k_detect_dtype<<<1,256,0,stream>>>((const unsigned short*)embed, dflag);
  k_detect_isf<<<1,256,0,stream>>>((const unsigned char*)isf, dflag);
  k_zero_i<<<1,512,0,stream>>>(cnt);

  PDesc pd;
  const int srcidx[15] = {4,5,6,7, 9,10,11, 13,14,15, 17, 19,20,21, 23};
  const int sizes[15]  = {45056,1024,1024,1024, 3072,3072,3072, 5120,5120,5120,
                          320, 1024,1024,1024, 64};
  int cum = 0;
  for(int i=0;i<15;i++){ pd.src[i] = d_in[srcidx[i]]; pd.cum[i] = cum; cum += sizes[i]; }
  pd.cum[15] = cum;  // 76160
  k_params<<<(PTOT+255)/256, 256, 0, stream>>>(pd, paramF, dflag);

  k_cvt_bf<<<44, 256, 0, stream>>>(d_in[4],  W1B, 44*HID_, dflag);
  k_cvt_bf<<<320,256, 0, stream>>>(d_in[16], W4B, 5*HID_*64, dflag);
  k_cvt_bf<<<64, 256, 0, stream>>>(d_in[22], W6B, HID_*64, dflag);

  k_transpose<<<dim3((GRUK_/64)*(GRUN_/64),1), 256, 0, stream>>>(d_in[8],  WgT, GRUK_, GRUN_, dflag);
  k_transpose<<<dim3((DETER_/64)*(HID_/64),5), 256, 0, stream>>>(d_in[12], W3T, DETER_, HID_, dflag);
  k_transpose<<<dim3((OBSK_/64)*(HID_/64),1), 256, 0, stream>>>(d_in[18], W5T, OBSK_, HID_, dflag);

  k_z5e<<<1024,256,0,stream>>>(embed, W5T, z5eB, dflag);

  k_persist<<<256,512,0,stream>>>(action, isf, dflag, paramF, W1B, W4B, W6B,
                                  z5eB, WgT, W3T, W5T,
                                  A2, deterB, deter, determ,
                                  z2p, z3p, z5dp,
                                  d_out, ens_ix, cnt);
}